// Round 1
// baseline (224.665 us; speedup 1.0000x reference)
//
#include <hip/hip_runtime.h>
#include <hip/hip_bf16.h>

// Crop: out[i, j] = audio[i, j]            for j <  starts[i]
//       out[i, j] = audio[i, j + CROP_NUM] for j >= starts[i]
// B=128, L=262144, CROP_NUM=26214, OUT_LEN=235930.
// Memory-bound gather-copy: ~121 MB read + ~121 MB write => ~38us floor @6.3TB/s.

constexpr int B_ = 128;
constexpr int L_ = 262144;
constexpr int CROP_ = 26214;
constexpr int OUT_LEN_ = L_ - CROP_;                       // 235930
constexpr long long TOTAL_ = (long long)B_ * OUT_LEN_;     // 30,199,040 (divisible by 4)

__global__ __launch_bounds__(256) void crop_kernel(const float* __restrict__ audio,
                                                   const int* __restrict__ starts,
                                                   float* __restrict__ out) {
    long long t = (long long)blockIdx.x * blockDim.x + threadIdx.x;
    long long base = t * 4;
    if (base >= TOTAL_) return;

    int row = (int)(base / OUT_LEN_);
    long long row_base = (long long)row * OUT_LEN_;
    long long row_end  = row_base + OUT_LEN_;

    float r[4];
    if (base + 4 <= row_end) {
        // Common case: all 4 elements in one row.
        int col = (int)(base - row_base);
        int s = starts[row];                       // wave-uniform-ish broadcast
        const float* src = audio + (long long)row * L_;
#pragma unroll
        for (int k = 0; k < 4; ++k) {
            int c = col + k;
            r[k] = src[c + (c >= s ? CROP_ : 0)];
        }
    } else {
        // Row-boundary straddle: happens for at most B-1 groups total.
#pragma unroll
        for (int k = 0; k < 4; ++k) {
            long long f = base + k;
            int rw = (int)(f / OUT_LEN_);
            int c = (int)(f - (long long)rw * OUT_LEN_);
            int s = starts[rw];
            r[k] = audio[(long long)rw * L_ + c + (c >= s ? CROP_ : 0)];
        }
    }
    *reinterpret_cast<float4*>(out + base) = make_float4(r[0], r[1], r[2], r[3]);
}

extern "C" void kernel_launch(void* const* d_in, const int* in_sizes, int n_in,
                              void* d_out, int out_size, void* d_ws, size_t ws_size,
                              hipStream_t stream) {
    const float* audio = (const float*)d_in[0];
    const int* starts  = (const int*)d_in[1];
    float* out = (float*)d_out;

    long long n_groups = TOTAL_ / 4;                       // 7,549,760
    int block = 256;
    int grid = (int)((n_groups + block - 1) / block);      // 29492
    crop_kernel<<<grid, block, 0, stream>>>(audio, starts, out);
}

// Round 2
// 223.970 us; speedup vs baseline: 1.0031x; 1.0031x over previous
//
#include <hip/hip_runtime.h>
#include <hip/hip_bf16.h>

// Crop: out[i, j] = audio[i, j]            for j <  starts[i]
//       out[i, j] = audio[i, j + CROP_NUM] for j >= starts[i]
// B=128, L=262144, CROP_NUM=26214, OUT_LEN=235930.
// Memory-bound two-segment copy per row: ~121 MB read + ~121 MB write
// => ~38us floor @6.3TB/s achievable.
//
// Key: per 4-element output group the source is contiguous unless starts[row]
// falls inside the group (<=1 group per row). Before the crop point src is
// 16B-aligned (float4 load); after it src is shifted by CROP*4=104856 bytes
// (8 mod 16) => 8B-aligned, use two float2 loads. Stores are always 16B-aligned
// float4. All flat indices fit in 32 bits (TOTAL=30.2M).

constexpr int B_ = 128;
constexpr int L_ = 262144;
constexpr int CROP_ = 26214;
constexpr int OUT_LEN_ = L_ - CROP_;                     // 235930
constexpr unsigned TOTAL_ = (unsigned)B_ * OUT_LEN_;     // 30,199,040 (div by 4)

__global__ __launch_bounds__(256) void crop_kernel(const float* __restrict__ audio,
                                                   const int* __restrict__ starts,
                                                   float* __restrict__ out) {
    unsigned t = blockIdx.x * 256u + threadIdx.x;
    unsigned base = t * 4u;
    if (base >= TOTAL_) return;

    unsigned row = base / (unsigned)OUT_LEN_;            // magic-mul, not real div
    unsigned col = base - row * (unsigned)OUT_LEN_;

    float4 v;
    if (col + 4u <= (unsigned)OUT_LEN_) {
        // Whole group inside one row (all but <=127 groups).
        int s = starts[row];                             // same addr across wave -> broadcast
        const float* src = audio + (size_t)row * L_ + col;
        if ((int)col + 4 <= s) {
            // Entirely before crop point: contiguous, 16B-aligned.
            v = *reinterpret_cast<const float4*>(src);
        } else if ((int)col >= s) {
            // Entirely at/after crop point: contiguous, 8B-aligned.
            const float2* p = reinterpret_cast<const float2*>(src + CROP_);
            float2 a = p[0];
            float2 b = p[1];
            v = make_float4(a.x, a.y, b.x, b.y);
        } else {
            // starts[row] inside this group: <=1 group per row in entire grid.
            float r[4];
#pragma unroll
            for (int k = 0; k < 4; ++k) {
                int c = (int)col + k;
                r[k] = src[k + (c >= s ? CROP_ : 0)];
            }
            v = make_float4(r[0], r[1], r[2], r[3]);
        }
    } else {
        // Group straddles a row boundary (<=127 groups total).
        float r[4];
#pragma unroll
        for (int k = 0; k < 4; ++k) {
            unsigned f = base + k;
            unsigned rw = f / (unsigned)OUT_LEN_;
            int c = (int)(f - rw * (unsigned)OUT_LEN_);
            int s = starts[rw];
            r[k] = audio[(size_t)rw * L_ + c + (c >= s ? CROP_ : 0)];
        }
        v = make_float4(r[0], r[1], r[2], r[3]);
    }
    *reinterpret_cast<float4*>(out + base) = v;
}

extern "C" void kernel_launch(void* const* d_in, const int* in_sizes, int n_in,
                              void* d_out, int out_size, void* d_ws, size_t ws_size,
                              hipStream_t stream) {
    const float* audio = (const float*)d_in[0];
    const int* starts  = (const int*)d_in[1];
    float* out = (float*)d_out;

    unsigned n_groups = TOTAL_ / 4u;                     // 7,549,760
    int block = 256;
    int grid = (int)((n_groups + (unsigned)block - 1) / (unsigned)block);  // 29492
    crop_kernel<<<grid, block, 0, stream>>>(audio, starts, out);
}